// Round 4
// baseline (130.889 us; speedup 1.0000x reference)
//
#include <hip/hip_runtime.h>
#include <hip/hip_bf16.h>
#include <float.h>

#define N_ROWS 8192
#define D_COLS 4096

typedef float f32x4 __attribute__((ext_vector_type(4)));

// Kernel 1: Err[row] = sum_j (in[row][j] - tg[row][j])^2
// One wave (64 lanes) per row, nontemporal (streaming, no cache-allocate)
// loads: data is read exactly once, so L2/L3 allocation is pure overhead
// and R1/R2 showed a structure-insensitive ~2.8 TB/s ceiling with 50% of
// traffic served by L3 at no speed benefit.
__global__ __launch_bounds__(256) void row_sqerr_kernel(
    const float* __restrict__ in, const float* __restrict__ tg,
    float* __restrict__ err) {
  const int row = (blockIdx.x << 2) | (threadIdx.x >> 6);
  const int lane = threadIdx.x & 63;
  const f32x4* a = (const f32x4*)(in + (size_t)row * D_COLS) + lane;
  const f32x4* b = (const f32x4*)(tg + (size_t)row * D_COLS) + lane;

  float acc0 = 0.f, acc1 = 0.f, acc2 = 0.f, acc3 = 0.f;
  f32x4 xa[8], xb[8];

#pragma unroll
  for (int s = 0; s < 2; ++s) {
    // issue 16 independent nontemporal loads
#pragma unroll
    for (int p = 0; p < 8; ++p) xa[p] = __builtin_nontemporal_load(&a[(s * 8 + p) * 64]);
#pragma unroll
    for (int p = 0; p < 8; ++p) xb[p] = __builtin_nontemporal_load(&b[(s * 8 + p) * 64]);
    // consume
#pragma unroll
    for (int p = 0; p < 8; ++p) {
      f32x4 d = xa[p] - xb[p];
      acc0 += d.x * d.x;
      acc1 += d.y * d.y;
      acc2 += d.z * d.z;
      acc3 += d.w * d.w;
    }
  }
  float acc = (acc0 + acc1) + (acc2 + acc3);
#pragma unroll
  for (int off = 32; off > 0; off >>= 1) acc += __shfl_down(acc, off);
  if (lane == 0) err[row] = acc;
}

// Kernel 2: sort Err, scan, find optimal split (Otsu-like), emit scalar loss.
// Single block, 1024 threads, 8 elements/thread.
__global__ __launch_bounds__(1024) void select_kernel(
    const float* __restrict__ err, float* __restrict__ out) {
  __shared__ float s[N_ROWS];        // 32 KB sorted errors
  __shared__ double dsum[1024];      // 8 KB scan of sums -> reused for obj
  __shared__ double dsq[1024];       // 8 KB scan of sumsq -> reused for c1@best
  __shared__ int sidx[1024];         // 4 KB argmin indices

  const int t = threadIdx.x;

  // load (coalesced)
#pragma unroll
  for (int m = 0; m < 8; ++m) s[(m << 10) | t] = err[(m << 10) | t];
  __syncthreads();

  // bitonic sort, ascending
  for (int k = 2; k <= N_ROWS; k <<= 1) {
    for (int j = k >> 1; j > 0; j >>= 1) {
      __syncthreads();
#pragma unroll
      for (int m = 0; m < 8; ++m) {
        int i = (m << 10) | t;
        int ixj = i ^ j;
        if (ixj > i) {
          float a = s[i], b = s[ixj];
          bool up = ((i & k) == 0);
          if ((a > b) == up) { s[i] = b; s[ixj] = a; }
        }
      }
    }
  }
  __syncthreads();

  // per-thread local sums over its 8 consecutive sorted elements
  float vals[8];
  double lsum = 0.0, lsq = 0.0;
#pragma unroll
  for (int k = 0; k < 8; ++k) {
    float v = s[t * 8 + k];
    vals[k] = v;
    lsum += (double)v;
    lsq += (double)v * (double)v;
  }
  dsum[t] = lsum;
  dsq[t] = lsq;
  __syncthreads();

  // Hillis-Steele inclusive scan over 1024 thread-totals (double)
  for (int off = 1; off < 1024; off <<= 1) {
    double a = (t >= off) ? dsum[t - off] : 0.0;
    double b = (t >= off) ? dsq[t - off] : 0.0;
    __syncthreads();
    dsum[t] += a;
    dsq[t] += b;
    __syncthreads();
  }

  const double total = dsum[1023];
  const double total_sq = dsq[1023];
  double c1 = dsum[t] - lsum;  // exclusive prefix
  double q1 = dsq[t] - lsq;
  __syncthreads();  // done reading scan results; LDS will be reused

  const double nf = (double)N_ROWS;
  const double all_mean = total / nf;
  const double Sb = total_sq - nf * all_mean * all_mean;

  double best = DBL_MAX;
  int bidx = N_ROWS;  // sentinel larger than any valid index
  double bc1 = 0.0;
#pragma unroll
  for (int k = 0; k < 8; ++k) {
    int i = t * 8 + k;
    double v = (double)vals[k];
    c1 += v;
    q1 += v * v;
    if (i <= N_ROWS - 2) {  // split indices 0..N-2 (n1 = 1..N-1)
      double n1 = (double)(i + 1);
      double n2 = nf - n1;
      double mean1 = c1 / n1;
      double mean2 = (total - c1) / n2;
      double Sw1 = q1 - n1 * mean1 * mean1;
      double Sw2 = (total_sq - q1) - n2 * mean2 * mean2;
      double obj = (Sw1 + Sw2) / Sb;
      if (obj < best) { best = obj; bidx = i; bc1 = c1; }
    }
  }

  // argmin tree-reduce (first-index tie-break)
  dsum[t] = best;
  dsq[t] = bc1;
  sidx[t] = bidx;
  for (int off = 512; off > 0; off >>= 1) {
    __syncthreads();
    if (t < off) {
      double o2 = dsum[t + off];
      int i2 = sidx[t + off];
      if (o2 < dsum[t] || (o2 == dsum[t] && i2 < sidx[t])) {
        dsum[t] = o2;
        sidx[t] = i2;
        dsq[t] = dsq[t + off];
      }
    }
  }
  __syncthreads();
  if (t == 0) {
    double opt_obj = dsum[0];
    int i_opt = sidx[0];
    double inlier_sum = dsq[0];
    double T = (double)(i_opt + 1);
    out[0] = (float)(inlier_sum / T + 0.1 * opt_obj);
  }
}

extern "C" void kernel_launch(void* const* d_in, const int* in_sizes, int n_in,
                              void* d_out, int out_size, void* d_ws, size_t ws_size,
                              hipStream_t stream) {
  const float* input = (const float*)d_in[0];
  const float* target = (const float*)d_in[1];
  float* out = (float*)d_out;
  float* err = (float*)d_ws;  // 8192 floats = 32 KB scratch

  row_sqerr_kernel<<<N_ROWS / 4, 256, 0, stream>>>(input, target, err);
  select_kernel<<<1, 1024, 0, stream>>>(err, out);
}

// Round 5
// 73.052 us; speedup vs baseline: 1.7917x; 1.7917x over previous
//
#include <hip/hip_runtime.h>
#include <hip/hip_bf16.h>
#include <float.h>
#include <limits.h>

#define N_ROWS 8192
#define D_COLS 4096

typedef float f32x4 __attribute__((ext_vector_type(4)));

// Kernel 1: Err[row] = sum_j (in[row][j] - tg[row][j])^2
// One wave per row, nontemporal loads (read-once stream, skip cache alloc).
__global__ __launch_bounds__(256) void row_sqerr_kernel(
    const float* __restrict__ in, const float* __restrict__ tg,
    float* __restrict__ err) {
  const int row = (blockIdx.x << 2) | (threadIdx.x >> 6);
  const int lane = threadIdx.x & 63;
  const f32x4* a = (const f32x4*)(in + (size_t)row * D_COLS) + lane;
  const f32x4* b = (const f32x4*)(tg + (size_t)row * D_COLS) + lane;

  float acc0 = 0.f, acc1 = 0.f, acc2 = 0.f, acc3 = 0.f;
  f32x4 xa[8], xb[8];

#pragma unroll
  for (int s = 0; s < 2; ++s) {
#pragma unroll
    for (int p = 0; p < 8; ++p) xa[p] = __builtin_nontemporal_load(&a[(s * 8 + p) * 64]);
#pragma unroll
    for (int p = 0; p < 8; ++p) xb[p] = __builtin_nontemporal_load(&b[(s * 8 + p) * 64]);
#pragma unroll
    for (int p = 0; p < 8; ++p) {
      f32x4 d = xa[p] - xb[p];
      acc0 += d.x * d.x;
      acc1 += d.y * d.y;
      acc2 += d.z * d.z;
      acc3 += d.w * d.w;
    }
  }
  float acc = (acc0 + acc1) + (acc2 + acc3);
#pragma unroll
  for (int off = 32; off > 0; off >>= 1) acc += __shfl_down(acc, off);
  if (lane == 0) err[row] = acc;
}

// Kernel 2: brute-force rank sort. rank(e) = #{j : (err[j],j) <lex (err[e],e)}
// is a bijection -> sorted[rank] = v. 512 blocks x 256 threads; each block
// stages all 8192 errs in LDS; 16 lanes cooperate per element, each lane
// scanning a 512-float segment with group-staggered float4 reads
// (broadcast within group; 4 groups/wave hit distinct bank quads).
__global__ __launch_bounds__(256) void rank_sort_kernel(
    const float* __restrict__ err, float* __restrict__ sorted) {
  __shared__ float s[N_ROWS];
  const int t = threadIdx.x;

#pragma unroll
  for (int k = 0; k < 32; ++k) s[t + (k << 8)] = err[t + (k << 8)];
  __syncthreads();

  const int g = t & 15;          // lane-group within element team
  const int le = t >> 4;         // local element 0..15
  const int e = (blockIdx.x << 4) | le;
  const float v = s[e];
  const f32x4* s4 = (const f32x4*)s;

  int cnt = 0;
#pragma unroll 8
  for (int k = 0; k < 128; ++k) {
    const int i4 = (g << 7) | ((k + g) & 127);
    const f32x4 c = s4[i4];
    const int j = i4 << 2;
    cnt += (c.x < v) || (c.x == v && (j + 0) < e);
    cnt += (c.y < v) || (c.y == v && (j + 1) < e);
    cnt += (c.z < v) || (c.z == v && (j + 2) < e);
    cnt += (c.w < v) || (c.w == v && (j + 3) < e);
  }
#pragma unroll
  for (int off = 1; off < 16; off <<= 1) cnt += __shfl_xor(cnt, off);
  if (g == 0) sorted[cnt] = v;
}

// Kernel 3: scan sorted errs (double), evaluate split objective, argmin,
// emit scalar loss. Single block, 1024 threads, shfl-based scans (6 barriers).
__global__ __launch_bounds__(1024) void scan_select_kernel(
    const float* __restrict__ sorted, float* __restrict__ out) {
  __shared__ double wsum[16], wsq[16];
  __shared__ double tot, totq;
  __shared__ double robj[16], rc1[16];
  __shared__ int ridx[16];

  const int t = threadIdx.x;
  const int lane = t & 63, wid = t >> 6;

  float vals[8];
  double lsum = 0.0, lsq = 0.0;
#pragma unroll
  for (int k = 0; k < 8; ++k) {
    float v = sorted[t * 8 + k];
    vals[k] = v;
    lsum += (double)v;
    lsq += (double)v * (double)v;
  }

  // wave-level inclusive scan of (lsum, lsq)
  double ssum = lsum, ssq = lsq;
#pragma unroll
  for (int off = 1; off < 64; off <<= 1) {
    double u = __shfl_up(ssum, off);
    double uq = __shfl_up(ssq, off);
    if (lane >= off) { ssum += u; ssq += uq; }
  }
  if (lane == 63) { wsum[wid] = ssum; wsq[wid] = ssq; }
  __syncthreads();

  // wave 0 scans the 16 wave totals -> exclusive prefixes + grand totals
  if (wid == 0) {
    double a = (lane < 16) ? wsum[lane] : 0.0;
    double b = (lane < 16) ? wsq[lane] : 0.0;
    double sa = a, sb = b;
#pragma unroll
    for (int off = 1; off < 16; off <<= 1) {
      double u = __shfl_up(sa, off);
      double uq = __shfl_up(sb, off);
      if (lane >= off) { sa += u; sb += uq; }
    }
    if (lane < 16) { wsum[lane] = sa - a; wsq[lane] = sb - b; }
    if (lane == 15) { tot = sa; totq = sb; }
  }
  __syncthreads();

  double c1 = wsum[wid] + (ssum - lsum);  // exclusive prefix before elem t*8
  double q1 = wsq[wid] + (ssq - lsq);
  const double total = tot, total_sq = totq;

  const double nf = (double)N_ROWS;
  const double all_mean = total / nf;
  const double inv_Sb = 1.0 / (total_sq - nf * all_mean * all_mean);

  double best = DBL_MAX;
  int bidx = INT_MAX;
  double bc1 = 0.0;
#pragma unroll
  for (int k = 0; k < 8; ++k) {
    int i = t * 8 + k;
    double v = (double)vals[k];
    c1 += v;
    q1 += v * v;
    if (i <= N_ROWS - 2) {
      double n1 = (double)(i + 1);
      double n2 = nf - n1;
      double mean1 = c1 / n1;
      double mean2 = (total - c1) / n2;
      double Sw1 = q1 - n1 * mean1 * mean1;
      double Sw2 = (total_sq - q1) - n2 * mean2 * mean2;
      double obj = (Sw1 + Sw2) * inv_Sb;
      if (obj < best) { best = obj; bidx = i; bc1 = c1; }
    }
  }

  // wave argmin (lexicographic (obj, idx))
#pragma unroll
  for (int off = 1; off < 64; off <<= 1) {
    double o2 = __shfl_xor(best, off);
    int i2 = __shfl_xor(bidx, off);
    double c2 = __shfl_xor(bc1, off);
    if (o2 < best || (o2 == best && i2 < bidx)) { best = o2; bidx = i2; bc1 = c2; }
  }
  if (lane == 0) { robj[wid] = best; ridx[wid] = bidx; rc1[wid] = bc1; }
  __syncthreads();

  if (wid == 0) {
    double o = (lane < 16) ? robj[lane] : DBL_MAX;
    int bi = (lane < 16) ? ridx[lane] : INT_MAX;
    double c = (lane < 16) ? rc1[lane] : 0.0;
#pragma unroll
    for (int off = 1; off < 16; off <<= 1) {
      double o2 = __shfl_xor(o, off);
      int i2 = __shfl_xor(bi, off);
      double c2 = __shfl_xor(c, off);
      if (o2 < o || (o2 == o && i2 < bi)) { o = o2; bi = i2; c = c2; }
    }
    if (lane == 0) {
      double T = (double)(bi + 1);
      out[0] = (float)(c / T + 0.1 * o);
    }
  }
}

extern "C" void kernel_launch(void* const* d_in, const int* in_sizes, int n_in,
                              void* d_out, int out_size, void* d_ws, size_t ws_size,
                              hipStream_t stream) {
  const float* input = (const float*)d_in[0];
  const float* target = (const float*)d_in[1];
  float* out = (float*)d_out;
  float* err = (float*)d_ws;                    // 8192 floats
  float* sorted = (float*)d_ws + N_ROWS;        // 8192 floats

  row_sqerr_kernel<<<N_ROWS / 4, 256, 0, stream>>>(input, target, err);
  rank_sort_kernel<<<512, 256, 0, stream>>>(err, sorted);
  scan_select_kernel<<<1, 1024, 0, stream>>>(sorted, out);
}